// Round 3
// baseline (437.036 us; speedup 1.0000x reference)
//
#include <hip/hip_runtime.h>
#include <math.h>

#define CCH 128
#define HH 64
#define WW 64
#define SHD 17
#define NSHIFT (SHD*SHD)   // 289

// ---- workspace layout ----
// float-index offsets:
#define OFF_KEY    0                         // 256 u32 monotone sim-max keys
#define OFF_NPART  256                       // 512*16 f  grd-norm partials [(h*8+csl)][n]
#define OFF_EPART  8448                      // 8*65536 f energy partials [csl][(n*64+h)*64+w]
#define OFF_SCALE  532736                    // 16*289 f
// byte offsets:
#define OFF_SATP_B 2162688                   // padded sat bf16: 8 x [h64][slot80][n16][c16]
#define SATP_SLICE_U16 (64*80*16*16)         // 1310720
#define OFF_GRDB_B (OFF_SATP_B + 8*SATP_SLICE_U16*2)   // 23134208
#define GRD_SLICE_U16 (64*64*16*16)          // 1048576
#define OFF_PART_B (OFF_GRDB_B + 8*GRD_SLICE_U16*2)    // 39911424
#define NBLK_CORR 576                        // csl8 x (8 grp x 8 strip + 8 light)
// part: per block 2 x 17 x 4 x 64 floats = 8704; total 576*8704*4 B = 20.1 MB

typedef __bf16 bf16x8 __attribute__((ext_vector_type(8)));
typedef float floatx4 __attribute__((ext_vector_type(4)));
typedef unsigned short ushort8 __attribute__((ext_vector_type(8)));

#define AS1 __attribute__((address_space(1)))
#define AS3 __attribute__((address_space(3)))

__device__ inline unsigned short f2bf(float f) {
    unsigned x = __float_as_uint(f);
    unsigned r = x + 0x7FFFu + ((x >> 16) & 1u);   // RNE
    return (unsigned short)(r >> 16);
}

// ---------------- K1: convert + transpose + norm/energy partials ----------
// grid: 1024 = tensor2 x h64 x csl8.  No atomics, no pre-zero needed.
__global__ __launch_bounds__(256) void k_prep(const float* __restrict__ sat,
                                              const float* __restrict__ grd,
                                              float* __restrict__ ws) {
    __shared__ unsigned short tile[64 * 256];   // 32 KB: [w][ (n+w)&15 ][c16]
    __shared__ float nred[16];
    int b = blockIdx.x;
    int tensor = b >> 9, h = (b >> 3) & 63, csl = b & 7;
    const float* src = tensor ? grd : sat;
    unsigned short* dstS = (unsigned short*)((char*)ws + OFF_SATP_B);
    unsigned short* dstG = (unsigned short*)((char*)ws + OFF_GRDB_B);
    int t = threadIdx.x;
    int n = t >> 4, wq = t & 15;

    float en0 = 0.f, en1 = 0.f, en2 = 0.f, en3 = 0.f;
    const float* base = src + ((size_t)(n * CCH + csl * 16) * 4096) + h * 64 + wq * 4;
    int w0 = wq * 4;
    #pragma unroll
    for (int c = 0; c < 16; ++c) {
        float4 v = *(const float4*)(base + (size_t)c * 4096);
        en0 = fmaf(v.x, v.x, en0); en1 = fmaf(v.y, v.y, en1);
        en2 = fmaf(v.z, v.z, en2); en3 = fmaf(v.w, v.w, en3);
        tile[(w0 + 0) * 256 + ((n + w0 + 0) & 15) * 16 + c] = f2bf(v.x);
        tile[(w0 + 1) * 256 + ((n + w0 + 1) & 15) * 16 + c] = f2bf(v.y);
        tile[(w0 + 2) * 256 + ((n + w0 + 2) & 15) * 16 + c] = f2bf(v.z);
        tile[(w0 + 3) * 256 + ((n + w0 + 3) & 15) * 16 + c] = f2bf(v.w);
    }

    if (tensor == 0) {
        float* eg = ws + OFF_EPART + (size_t)csl * 65536 + ((size_t)n * 64 + h) * 64 + w0;
        *(float4*)eg = make_float4(en0, en1, en2, en3);   // plain partial store
    } else {
        float s = en0 + en1 + en2 + en3;
        #pragma unroll
        for (int off = 8; off; off >>= 1) s += __shfl_xor(s, off);  // 16-lane group
        if (wq == 0) nred[n] = s;
    }

    __syncthreads();
    if (tensor == 1 && t < 16)
        ws[OFF_NPART + (size_t)(h * 8 + csl) * 16 + t] = nred[t];

    unsigned short* dst = tensor
        ? dstG + (size_t)csl * GRD_SLICE_U16 + (size_t)h * 16384
        : dstS + (size_t)csl * SATP_SLICE_U16 + ((size_t)h * 80 + 8) * 256;
    #pragma unroll
    for (int i = 0; i < 8; ++i) {
        int o = i * 256 + t;
        int w = o >> 5, nn = (o >> 1) & 15, c8 = o & 1;
        ushort8 val = *(ushort8*)&tile[w * 256 + ((nn + w) & 15) * 16 + c8 * 8];
        *(ushort8*)&dst[(size_t)o * 8] = val;
    }
    if (tensor == 0) {
        ushort8 z = (ushort8)0;
        #pragma unroll
        for (int i = 0; i < 2; ++i) {
            int o = i * 256 + t;
            int slot = o >> 5, wi = o & 31;
            int ps = slot < 8 ? slot : slot + 64;
            *(ushort8*)&dstS[(size_t)csl * SATP_SLICE_U16 +
                             ((size_t)h * 80 + ps) * 256 + wi * 8] = z;
        }
    }
}

// ---------------- K2: energy partial-sum -> windowed scale; zero keys -----
__global__ __launch_bounds__(320) void k_scale(float* __restrict__ ws) {
    __shared__ float E[64 * 64];
    __shared__ float R[64 * 17];
    int m = blockIdx.x;
    int t = threadIdx.x;
    float* scale = ws + OFF_SCALE + (size_t)m * NSHIFT;
    if (t < 16) ((unsigned*)ws)[OFF_KEY + m * 16 + t] = 0u;   // zero sim-max keys
    const float* ep = ws + OFF_EPART + (size_t)m * 4096;
    for (int i = t; i < 4096; i += 320) {
        float s = 0.f;
        #pragma unroll
        for (int csl = 0; csl < 8; ++csl) s += ep[(size_t)csl * 65536 + i];
        E[i] = s;
    }
    __syncthreads();
    for (int i = t; i < 64 * 17; i += 320) {
        int y = i / 17, j = i % 17;
        int x0 = max(0, j - 8), x1 = min(64, j + 56);
        float s = 0.f;
        for (int x = x0; x < x1; ++x) s += E[y * 64 + x];
        R[i] = s;
    }
    __syncthreads();
    for (int idx = t; idx < NSHIFT; idx += 320) {
        int ii = idx / 17, j = idx % 17;
        int y0 = max(0, ii - 8), y1 = min(64, ii + 56);
        float s = 0.f;
        for (int y = y0; y < y1; ++y) s += R[y * 17 + j];
        scale[idx] = 1.f / fmaxf(sqrtf(s), 1e-12f);
    }
}

// ---------------- K3: MFMA cross-correlation (dual-dyi per staged row) ----
// Restructure rationale (round-1 post-mortem): matrix-pipe floor is 29 us;
// round-1 measured 62 us at MfmaUtil 48% with LDS/VALU all slack -> loss is
// dispatch granularity (1088 blocks / 512 slots = 2.1 rounds + variance) and
// 17x re-staging of each sat row (one dyi per block).
// Now: each wave computes TWO dyi per staged row (acc[2][17]; grd rows hg and
// hg-1 reuse every A fragment) -> row-steps halve (8128 -> 4320 stages) and
// MFMA per step doubles. Grid = 8 csl x (8 dyi-pairs x 8 row-strips) = 512
// uniform heavy blocks = EXACTLY 2 blocks/CU x 1 round; 64 half-weight
// dyi=16 blocks are dispatched last to backfill the tail.
// VGPR budget: acc 2x17x4 (AGPR) + Bc 2x8x4 + A/An + addr ~= 250 <= 256.
__global__ __launch_bounds__(256, 2) void k_corr(const unsigned short* __restrict__ satp,
                                                 const unsigned short* __restrict__ grdb,
                                                 float* __restrict__ part) {
    __shared__ alignas(16) unsigned char smem[81920];
    int b = blockIdx.x;
    int csl  = b & 7;                  // XCD affinity: all blocks of csl c on XCD c
    int rest = b >> 3;                 // 0..71
    int light = rest >= 64;            // dyi=16 singleton blocks, dispatched last
    int grp   = light ? 8 : (rest & 7);
    int strip = light ? (rest - 64) : (rest >> 3);
    int d0 = grp * 2;                  // dyi pair (d0, d0+1); light: d0=16 only
    int t = threadIdx.x;
    int wv = t >> 6, l = t & 63;
    int m16 = l & 15, q = l >> 4, jl = q >> 1, c8 = q & 1;
    int wbase = wv * 16;

    const unsigned short* sats = satp + (size_t)csl * SATP_SLICE_U16;
    const unsigned short* grds = grdb + (size_t)csl * GRD_SLICE_U16;
    const unsigned short* goff = grds + ((wbase + jl) * 16 + m16) * 16 + c8 * 8;

    // valid sat rows: dyi d needs hg = hs+8-d in [0,64) -> hs in [d-8, d+56)
    int s0 = strip * 8;
    int lo = light ? 8 : max(0, d0 - 8);
    int hi = light ? 64 : min(64, d0 + 57);
    int hs_first = max(s0, lo), hs_end = min(s0 + 8, hi);

    floatx4 acc0[17], acc1[17];
    #pragma unroll
    for (int d = 0; d < 17; ++d) { acc0[d] = (floatx4)0.f; acc1[d] = (floatx4)0.f; }

    #define STAGE(hs, p)                                                            \
        do {                                                                        \
            _Pragma("unroll")                                                       \
            for (int i_ = 0; i_ < 10; ++i_) {                                       \
                const unsigned short* g_ = sats + (size_t)(hs) * 20480              \
                                         + wv * 5120 + i_ * 512 + l * 8;            \
                __builtin_amdgcn_global_load_lds((AS1 void*)(unsigned short*)g_,    \
                    (AS3 void*)(smem + (p) * 40960 + wv * 10240 + i_ * 1024 + l * 16), \
                    16, 0, 0);                                                      \
            }                                                                       \
        } while (0)

    // B fragments for staged row hs: dyi d0 -> grd row hg0 = hs+8-d0,
    // dyi d0+1 -> hg0-1.  Out-of-range row -> zero fragments (rare edges).
    bf16x8 Bc0[8], Bc1[8];
    #define LOADB(hs_, DO_G2)                                                       \
        do {                                                                        \
            int hg0_ = (hs_) + 8 - d0;                                              \
            if ((unsigned)hg0_ < 64u) {                                             \
                _Pragma("unroll")                                                   \
                for (int bi = 0; bi < 8; ++bi)                                      \
                    Bc0[bi] = *(const bf16x8*)(goff + (size_t)hg0_ * 16384 + bi * 512); \
            } else {                                                                \
                _Pragma("unroll")                                                   \
                for (int bi = 0; bi < 8; ++bi)                                      \
                    Bc0[bi] = __builtin_bit_cast(bf16x8, (ushort8)0);               \
            }                                                                       \
            if (DO_G2) {                                                            \
                int hg1_ = hg0_ - 1;                                                \
                if ((unsigned)hg1_ < 64u) {                                         \
                    _Pragma("unroll")                                               \
                    for (int bi = 0; bi < 8; ++bi)                                  \
                        Bc1[bi] = *(const bf16x8*)(goff + (size_t)hg1_ * 16384 + bi * 512); \
                } else {                                                            \
                    _Pragma("unroll")                                               \
                    for (int bi = 0; bi < 8; ++bi)                                  \
                        Bc1[bi] = __builtin_bit_cast(bf16x8, (ushort8)0);           \
                }                                                                   \
            }                                                                       \
        } while (0)

    #define ROWBODY(DO_G2)                                                          \
        do {                                                                        \
            const unsigned char* aptr = smem + p * 40960 + jl * 512 + m16 * 32 + c8 * 16; \
            bf16x8 A = *(const bf16x8*)(aptr + (size_t)wbase * 512);                \
            _Pragma("unroll")                                                       \
            for (int wo = 0; wo < 31; ++wo) {                                       \
                bf16x8 An = A;                                                      \
                if (wo < 30) An = *(const bf16x8*)(aptr + (size_t)(wbase + wo + 1) * 512); \
                _Pragma("unroll")                                                   \
                for (int bi = 0; bi < 8; ++bi) {                                    \
                    const int dxi = wo - 2 * bi;   /* compile-time after unroll */  \
                    if (dxi >= 0 && dxi <= 16) {                                    \
                        acc0[dxi] = __builtin_amdgcn_mfma_f32_16x16x32_bf16(A, Bc0[bi], acc0[dxi], 0, 0, 0); \
                        if (DO_G2)                                                  \
                            acc1[dxi] = __builtin_amdgcn_mfma_f32_16x16x32_bf16(A, Bc1[bi], acc1[dxi], 0, 0, 0); \
                    }                                                               \
                }                                                                   \
                A = An;                                                             \
            }                                                                       \
        } while (0)

    if (hs_first < hs_end) {
        STAGE(hs_first, 0);
        if (light) LOADB(hs_first, 0); else LOADB(hs_first, 1);
        for (int hs = hs_first; hs < hs_end; ++hs) {
            __syncthreads();                 // staged buf[p] + Bc ready
            int p = (hs - hs_first) & 1;
            if (hs + 1 < hs_end) STAGE(hs + 1, p ^ 1);
            if (light) ROWBODY(0); else ROWBODY(1);
            if (hs + 1 < hs_end) {           // reload B after last use; drains at
                if (light) LOADB(hs + 1, 0); else LOADB(hs + 1, 1);   // next barrier
            }
        }
    }
    #undef STAGE
    #undef LOADB
    #undef ROWBODY

    // ---- cross-wave reduction epilogue, one pass per dyi ----
    __syncthreads();                    // all waves done with staged smem
    float* red = (float*)smem;          // 4*68*64*4 = 69632 B <= 81920
    float* pw = part + (size_t)b * 8704;
    #pragma unroll
    for (int dxi = 0; dxi < 17; ++dxi)
        #pragma unroll
        for (int r = 0; r < 4; ++r)
            red[(size_t)(wv * 68 + dxi * 4 + r) * 64 + l] = acc0[dxi][r];
    __syncthreads();
    #pragma unroll
    for (int k = 0; k < 17; ++k) {
        int row = wv * 17 + k;
        float s = red[(size_t)(0 * 68 + row) * 64 + l]
                + red[(size_t)(1 * 68 + row) * 64 + l]
                + red[(size_t)(2 * 68 + row) * 64 + l]
                + red[(size_t)(3 * 68 + row) * 64 + l];
        pw[(size_t)row * 64 + l] = s;
    }
    if (!light) {                       // g=1 region only read for real dyi
        __syncthreads();
        #pragma unroll
        for (int dxi = 0; dxi < 17; ++dxi)
            #pragma unroll
            for (int r = 0; r < 4; ++r)
                red[(size_t)(wv * 68 + dxi * 4 + r) * 64 + l] = acc1[dxi][r];
        __syncthreads();
        #pragma unroll
        for (int k = 0; k < 17; ++k) {
            int row = wv * 17 + k;
            float s = red[(size_t)(0 * 68 + row) * 64 + l]
                    + red[(size_t)(1 * 68 + row) * 64 + l]
                    + red[(size_t)(2 * 68 + row) * 64 + l]
                    + red[(size_t)(3 * 68 + row) * 64 + l];
            pw[4352 + (size_t)row * 64 + l] = s;
        }
    }
}

// ---------------- K4: reduce partials + scale + sim-max -------------------
__global__ void k_reduce(const float* __restrict__ part, float* __restrict__ ws) {
    int b = blockIdx.x;            // 289
    int dyi = b / 17, dxi = b % 17;
    int grp = dyi >> 1, g = dyi & 1;    // dyi=16 -> grp=8, g=0
    int t = threadIdx.x;
    int l = t & 63, r = t >> 6;
    size_t eo = (size_t)g * 4352 + (size_t)(dxi * 4 + r) * 64 + l;
    float s = 0.f;
    for (int strip = 0; strip < 8; ++strip) {
        int rest = (grp == 8) ? (64 + strip) : (strip * 8 + grp);
        #pragma unroll
        for (int csl = 0; csl < 8; ++csl)
            s += part[(size_t)(csl + 8 * rest) * 8704 + eo];
    }
    int n = l & 15, q = l >> 4, m = q * 4 + r;
    float val = s * ws[OFF_SCALE + m * NSHIFT + dyi * 17 + dxi];
    int iv = __float_as_int(val);
    unsigned key = (iv >= 0) ? ((unsigned)iv | 0x80000000u) : (unsigned)(~iv);
    atomicMax((unsigned*)ws + OFF_KEY + m * 16 + n, key);
}

// ---------------- K5: epilogue -> 3 scalars ----------------
__global__ void k_final(const float* __restrict__ ws, float* __restrict__ out) {
    const unsigned* keys = (const unsigned*)ws + OFF_KEY;
    __shared__ float dist_s[256];
    __shared__ float pos_s[16];
    __shared__ float red[256];
    __shared__ float minv[16];
    __shared__ float norms_s[16];
    int t = threadIdx.x;          // t = m*16 + n
    int m = t >> 4, n = t & 15;

    if (t < 16) {                  // grd sumsq: sum 512 partials
        float s = 0.f;
        const float* np = ws + OFF_NPART + t;
        #pragma unroll 8
        for (int j = 0; j < 512; ++j) s += np[(size_t)j * 16];
        norms_s[t] = s;
    }
    __syncthreads();

    unsigned u = keys[t];
    int iv = (u & 0x80000000u) ? (int)(u & 0x7fffffffu) : ~(int)u;
    float best = __int_as_float(iv);
    float Ng  = sqrtf(norms_s[n]);
    float sim = best / fmaxf(Ng, 1e-12f);
    float d   = 2.f - 2.f * sim;
    dist_s[t] = d;
    if (m == n) pos_s[m] = d;
    __syncthreads();

    float x1 = (pos_s[n] - d) * 10.f;
    float x2 = (pos_s[m] - d) * 10.f;
    float sp1 = x1 > 20.f ? x1 : log1pf(expf(x1));
    float sp2 = x2 > 20.f ? x2 : log1pf(expf(x2));
    red[t] = sp1 + sp2;
    __syncthreads();
    for (int off = 128; off; off >>= 1) {
        if (t < off) red[t] += red[t + off];
        __syncthreads();
    }
    if (t < 16) {
        float mv = 1e30f;
        for (int nn = 0; nn < 16; ++nn) mv = fminf(mv, dist_s[t * 16 + nn]);
        minv[t] = mv;
    }
    __syncthreads();
    if (t == 0) {
        float psum = 0.f, msum = 0.f;
        for (int qq = 0; qq < 16; ++qq) { psum += pos_s[qq]; msum += minv[qq]; }
        out[0] = red[0] / 48.f;
        out[1] = psum / 16.f;
        out[2] = msum / 16.f;
    }
}

extern "C" void kernel_launch(void* const* d_in, const int* in_sizes, int n_in,
                              void* d_out, int out_size, void* d_ws, size_t ws_size,
                              hipStream_t stream) {
    const float* sat = (const float*)d_in[0];
    const float* grd = (const float*)d_in[1];
    float* out = (float*)d_out;
    float* ws  = (float*)d_ws;
    const unsigned short* satp = (const unsigned short*)((char*)d_ws + OFF_SATP_B);
    const unsigned short* grdb = (const unsigned short*)((char*)d_ws + OFF_GRDB_B);
    float* part = (float*)((char*)d_ws + OFF_PART_B);

    k_prep  <<<1024,      256, 0, stream>>>(sat, grd, ws);
    k_scale <<<16,        320, 0, stream>>>(ws);
    k_corr  <<<NBLK_CORR, 256, 0, stream>>>(satp, grdb, part);
    k_reduce<<<NSHIFT,    256, 0, stream>>>(part, ws);
    k_final <<<1,         256, 0, stream>>>(ws, out);
}

// Round 5
// 201.758 us; speedup vs baseline: 2.1661x; 2.1661x over previous
//
#include <hip/hip_runtime.h>
#include <math.h>

#define CCH 128
#define HH 64
#define WW 64
#define SHD 17
#define NSHIFT (SHD*SHD)   // 289

// ---- workspace layout ----
// float-index offsets:
#define OFF_KEY    0                         // 256 u32 monotone sim-max keys
#define OFF_NPART  256                       // 512*16 f  grd-norm partials [(h*8+csl)][n]
#define OFF_EPART  8448                      // 8*65536 f energy partials [csl][(n*64+h)*64+w]
#define OFF_SCALE  532736                    // 16*289 f
// byte offsets:
#define OFF_SATP_B 2162688                   // padded sat bf16: 8 x [h64][slot80][n16][c16]
#define SATP_SLICE_U16 (64*80*16*16)         // 1310720
#define OFF_GRDB_B (OFF_SATP_B + 8*SATP_SLICE_U16*2)   // 23134208
#define GRD_SLICE_U16 (64*64*16*16)          // 1048576
#define OFF_PART_B (OFF_GRDB_B + 8*GRD_SLICE_U16*2)    // 39911424
#define NBLK_CORR 1016                       // csl8 x 127 uniform 8-row blocks
// part: slot (dyi*8+strip)*8+csl -> 17*8*8 = 1088 slots x 4352 f = 18.9 MB
// slots (dyi=0,strip=7) and (dyi=16,strip=0) are statically empty (skipped).

typedef __bf16 bf16x8 __attribute__((ext_vector_type(8)));
typedef float floatx4 __attribute__((ext_vector_type(4)));
typedef unsigned short ushort8 __attribute__((ext_vector_type(8)));

#define AS1 __attribute__((address_space(1)))
#define AS3 __attribute__((address_space(3)))

__device__ inline unsigned short f2bf(float f) {
    unsigned x = __float_as_uint(f);
    unsigned r = x + 0x7FFFu + ((x >> 16) & 1u);   // RNE
    return (unsigned short)(r >> 16);
}

// ---------------- K1: convert + transpose + norm/energy partials ----------
// grid: 1024 = tensor2 x h64 x csl8.  No atomics, no pre-zero needed.
__global__ __launch_bounds__(256) void k_prep(const float* __restrict__ sat,
                                              const float* __restrict__ grd,
                                              float* __restrict__ ws) {
    __shared__ unsigned short tile[64 * 256];   // 32 KB: [w][ (n+w)&15 ][c16]
    __shared__ float nred[16];
    int b = blockIdx.x;
    int tensor = b >> 9, h = (b >> 3) & 63, csl = b & 7;
    const float* src = tensor ? grd : sat;
    unsigned short* dstS = (unsigned short*)((char*)ws + OFF_SATP_B);
    unsigned short* dstG = (unsigned short*)((char*)ws + OFF_GRDB_B);
    int t = threadIdx.x;
    int n = t >> 4, wq = t & 15;

    float en0 = 0.f, en1 = 0.f, en2 = 0.f, en3 = 0.f;
    const float* base = src + ((size_t)(n * CCH + csl * 16) * 4096) + h * 64 + wq * 4;
    int w0 = wq * 4;
    #pragma unroll
    for (int c = 0; c < 16; ++c) {
        float4 v = *(const float4*)(base + (size_t)c * 4096);
        en0 = fmaf(v.x, v.x, en0); en1 = fmaf(v.y, v.y, en1);
        en2 = fmaf(v.z, v.z, en2); en3 = fmaf(v.w, v.w, en3);
        tile[(w0 + 0) * 256 + ((n + w0 + 0) & 15) * 16 + c] = f2bf(v.x);
        tile[(w0 + 1) * 256 + ((n + w0 + 1) & 15) * 16 + c] = f2bf(v.y);
        tile[(w0 + 2) * 256 + ((n + w0 + 2) & 15) * 16 + c] = f2bf(v.z);
        tile[(w0 + 3) * 256 + ((n + w0 + 3) & 15) * 16 + c] = f2bf(v.w);
    }

    if (tensor == 0) {
        float* eg = ws + OFF_EPART + (size_t)csl * 65536 + ((size_t)n * 64 + h) * 64 + w0;
        *(float4*)eg = make_float4(en0, en1, en2, en3);   // plain partial store
    } else {
        float s = en0 + en1 + en2 + en3;
        #pragma unroll
        for (int off = 8; off; off >>= 1) s += __shfl_xor(s, off);  // 16-lane group
        if (wq == 0) nred[n] = s;
    }

    __syncthreads();
    if (tensor == 1 && t < 16)
        ws[OFF_NPART + (size_t)(h * 8 + csl) * 16 + t] = nred[t];

    unsigned short* dst = tensor
        ? dstG + (size_t)csl * GRD_SLICE_U16 + (size_t)h * 16384
        : dstS + (size_t)csl * SATP_SLICE_U16 + ((size_t)h * 80 + 8) * 256;
    #pragma unroll
    for (int i = 0; i < 8; ++i) {
        int o = i * 256 + t;
        int w = o >> 5, nn = (o >> 1) & 15, c8 = o & 1;
        ushort8 val = *(ushort8*)&tile[w * 256 + ((nn + w) & 15) * 16 + c8 * 8];
        *(ushort8*)&dst[(size_t)o * 8] = val;
    }
    if (tensor == 0) {
        ushort8 z = (ushort8)0;
        #pragma unroll
        for (int i = 0; i < 2; ++i) {
            int o = i * 256 + t;
            int slot = o >> 5, wi = o & 31;
            int ps = slot < 8 ? slot : slot + 64;
            *(ushort8*)&dstS[(size_t)csl * SATP_SLICE_U16 +
                             ((size_t)h * 80 + ps) * 256 + wi * 8] = z;
        }
    }
}

// ---------------- K2: energy partial-sum -> windowed scale; zero keys -----
__global__ __launch_bounds__(320) void k_scale(float* __restrict__ ws) {
    __shared__ float E[64 * 64];
    __shared__ float R[64 * 17];
    int m = blockIdx.x;
    int t = threadIdx.x;
    float* scale = ws + OFF_SCALE + (size_t)m * NSHIFT;
    if (t < 16) ((unsigned*)ws)[OFF_KEY + m * 16 + t] = 0u;   // zero sim-max keys
    const float* ep = ws + OFF_EPART + (size_t)m * 4096;
    for (int i = t; i < 4096; i += 320) {
        float s = 0.f;
        #pragma unroll
        for (int csl = 0; csl < 8; ++csl) s += ep[(size_t)csl * 65536 + i];
        E[i] = s;
    }
    __syncthreads();
    for (int i = t; i < 64 * 17; i += 320) {
        int y = i / 17, j = i % 17;
        int x0 = max(0, j - 8), x1 = min(64, j + 56);
        float s = 0.f;
        for (int x = x0; x < x1; ++x) s += E[y * 64 + x];
        R[i] = s;
    }
    __syncthreads();
    for (int idx = t; idx < NSHIFT; idx += 320) {
        int ii = idx / 17, j = idx % 17;
        int y0 = max(0, ii - 8), y1 = min(64, ii + 56);
        float s = 0.f;
        for (int y = y0; y < y1; ++y) s += R[y * 17 + j];
        scale[idx] = 1.f / fmaxf(sqrtf(s), 1e-12f);
    }
}

// ---------------- K3: MFMA cross-correlation (uniform 8-row blocks) -------
// Round-3 post-mortem: dual-acc spilled (1.2 GB scratch). Round-4 theory:
// R0/R1's 48% MfmaUtil is MAKESPAN granularity -- 1088 near-uniform blocks
// over 512 co-resident slots = 3 sequential waves (last 87% empty) since
// backfill can't split uniform blocks. Rows per dyi = 64-|dyi-8|; the short
// edge strips pair exactly: (dyi=k,strip7)=k rows + (dyi=8+k,strip0)=8-k
// rows. Merge each pair into ONE block running the two segments
// SEQUENTIALLY (single acc set, flush+rezero between) -> 127 blocks/csl,
// every block exactly 8 rows -> grid 1016 = 1.984 rounds of 512 slots.
// Merged blocks dispatched first. ROWBODY = R0's simple form (best
// measured, lowest VGPR). Epilogue: cross-wave LDS reduce, part 18.9 MB.
__global__ __launch_bounds__(256, 2) void k_corr(const unsigned short* __restrict__ satp,
                                                 const unsigned short* __restrict__ grdb,
                                                 float* __restrict__ part) {
    __shared__ alignas(16) unsigned char smem[81920];
    int b = blockIdx.x;
    int csl = b & 7;                   // XCD low bits: csl-locality per XCD
    int r = b >> 3;                    // 0..126
    int nseg, d0a, s0a, d0b = 0, s0b = 0;
    if (r < 7) {                       // merged: (k, strip7) + (8+k, strip0)
        int k = r + 1;
        nseg = 2; d0a = k; s0a = 7; d0b = 8 + k; s0b = 0;
    } else {
        int rp = r - 7; nseg = 1;
        if (rp < 56)      { d0a = rp / 7;              s0a = rp % 7; }
        else if (rp < 64) { d0a = 8;                   s0a = rp - 56; }
        else              { int qq = rp - 64; d0a = 9 + qq / 7; s0a = 1 + qq % 7; }
    }
    int t = threadIdx.x;
    int wv = t >> 6, l = t & 63;
    int m16 = l & 15, q = l >> 4, jl = q >> 1, c8 = q & 1;
    int wbase = wv * 16;

    const unsigned short* sats = satp + (size_t)csl * SATP_SLICE_U16;
    const unsigned short* grds = grdb + (size_t)csl * GRD_SLICE_U16;
    const unsigned short* goff = grds + ((wbase + jl) * 16 + m16) * 16 + c8 * 8;

    #define STAGE(hs, p)                                                            \
        do {                                                                        \
            _Pragma("unroll")                                                       \
            for (int i_ = 0; i_ < 10; ++i_) {                                       \
                const unsigned short* g_ = sats + (size_t)(hs) * 20480              \
                                         + wv * 5120 + i_ * 512 + l * 8;            \
                __builtin_amdgcn_global_load_lds((AS1 void*)(unsigned short*)g_,    \
                    (AS3 void*)(smem + (p) * 40960 + wv * 10240 + i_ * 1024 + l * 16), \
                    16, 0, 0);                                                      \
            }                                                                       \
        } while (0)

    for (int seg = 0; seg < nseg; ++seg) {
        int d0 = seg ? d0b : d0a;
        int st = seg ? s0b : s0a;
        int lo_d = max(0, d0 - 8), hi_d = min(64, d0 + 56);
        int hs_first = max(st * 8, lo_d), hs_end = min(st * 8 + 8, hi_d);

        floatx4 acc[17];
        #pragma unroll
        for (int d = 0; d < 17; ++d) acc[d] = (floatx4)0.f;

        if (seg)                        // prev flush's LDS reads retired before
            __syncthreads();            // STAGE overwrites the red region

        if (hs_first < hs_end) {
            STAGE(hs_first, 0);
            bf16x8 Bc[8], Bn[8];
            {   // grd row for dyi=d0 at sat row hs: hg = hs+8-d0, in [0,64) by construction
                int hg = hs_first + 8 - d0;
                #pragma unroll
                for (int bi = 0; bi < 8; ++bi)
                    Bc[bi] = *(const bf16x8*)(goff + (size_t)hg * 16384 + bi * 512);
            }
            for (int hs = hs_first; hs < hs_end; ++hs) {
                __syncthreads();                 // staged buf[p] ready
                int p = (hs - hs_first) & 1;
                if (hs + 1 < hs_end) {
                    STAGE(hs + 1, p ^ 1);
                    int hg2 = hs + 1 + 8 - d0;
                    #pragma unroll
                    for (int bi = 0; bi < 8; ++bi)
                        Bn[bi] = *(const bf16x8*)(goff + (size_t)hg2 * 16384 + bi * 512);
                }
                const unsigned char* aptr = smem + p * 40960 + jl * 512 + m16 * 32 + c8 * 16;
                bf16x8 A = *(const bf16x8*)(aptr + (size_t)wbase * 512);
                #pragma unroll
                for (int wo = 0; wo < 31; ++wo) {    // slot = wbase + wo (+jl)
                    bf16x8 An = A;
                    if (wo < 30) An = *(const bf16x8*)(aptr + (size_t)(wbase + wo + 1) * 512);
                    #pragma unroll
                    for (int bi = 0; bi < 8; ++bi) {
                        const int dxi = wo - 2 * bi;   // compile-time after unroll
                        if (dxi >= 0 && dxi <= 16)
                            acc[dxi] = __builtin_amdgcn_mfma_f32_16x16x32_bf16(A, Bc[bi], acc[dxi], 0, 0, 0);
                    }
                    A = An;
                }
                #pragma unroll
                for (int bi = 0; bi < 8; ++bi) Bc[bi] = Bn[bi];
            }
        }

        // ---- cross-wave reduction flush for this segment ----
        __syncthreads();                // all waves done reading staged smem
        float* red = (float*)smem;      // 4*68*64*4 = 69632 B <= 81920
        #pragma unroll
        for (int dxi = 0; dxi < 17; ++dxi)
            #pragma unroll
            for (int rr = 0; rr < 4; ++rr)
                red[(size_t)(wv * 68 + dxi * 4 + rr) * 64 + l] = acc[dxi][rr];
        __syncthreads();
        float* pw = part + (size_t)((d0 * 8 + st) * 8 + csl) * 4352;
        #pragma unroll
        for (int k = 0; k < 17; ++k) {
            int row = wv * 17 + k;
            float s = red[(size_t)(0 * 68 + row) * 64 + l]
                    + red[(size_t)(1 * 68 + row) * 64 + l]
                    + red[(size_t)(2 * 68 + row) * 64 + l]
                    + red[(size_t)(3 * 68 + row) * 64 + l];
            pw[(size_t)row * 64 + l] = s;
        }
    }
    #undef STAGE
}

// ---------------- K4: reduce partials + scale + sim-max -------------------
__global__ void k_reduce(const float* __restrict__ part, float* __restrict__ ws) {
    int b = blockIdx.x;            // 289
    int dyi = b / 17, dxi = b % 17;
    int t = threadIdx.x;
    int l = t & 63, r = t >> 6;
    size_t eo = (size_t)(dxi * 4 + r) * 64 + l;
    float s = 0.f;
    for (int st = 0; st < 8; ++st) {
        if ((dyi == 0 && st == 7) || (dyi == 16 && st == 0)) continue;  // empty slots
        #pragma unroll
        for (int csl = 0; csl < 8; ++csl)
            s += part[(size_t)((dyi * 8 + st) * 8 + csl) * 4352 + eo];
    }
    int n = l & 15, q = l >> 4, m = q * 4 + r;
    float val = s * ws[OFF_SCALE + m * NSHIFT + dyi * 17 + dxi];
    int iv = __float_as_int(val);
    unsigned key = (iv >= 0) ? ((unsigned)iv | 0x80000000u) : (unsigned)(~iv);
    atomicMax((unsigned*)ws + OFF_KEY + m * 16 + n, key);
}

// ---------------- K5: epilogue -> 3 scalars ----------------
__global__ void k_final(const float* __restrict__ ws, float* __restrict__ out) {
    const unsigned* keys = (const unsigned*)ws + OFF_KEY;
    __shared__ float dist_s[256];
    __shared__ float pos_s[16];
    __shared__ float red[256];
    __shared__ float minv[16];
    __shared__ float norms_s[16];
    int t = threadIdx.x;          // t = m*16 + n
    int m = t >> 4, n = t & 15;

    if (t < 16) {                  // grd sumsq: sum 512 partials
        float s = 0.f;
        const float* np = ws + OFF_NPART + t;
        #pragma unroll 8
        for (int j = 0; j < 512; ++j) s += np[(size_t)j * 16];
        norms_s[t] = s;
    }
    __syncthreads();

    unsigned u = keys[t];
    int iv = (u & 0x80000000u) ? (int)(u & 0x7fffffffu) : ~(int)u;
    float best = __int_as_float(iv);
    float Ng  = sqrtf(norms_s[n]);
    float sim = best / fmaxf(Ng, 1e-12f);
    float d   = 2.f - 2.f * sim;
    dist_s[t] = d;
    if (m == n) pos_s[m] = d;
    __syncthreads();

    float x1 = (pos_s[n] - d) * 10.f;
    float x2 = (pos_s[m] - d) * 10.f;
    float sp1 = x1 > 20.f ? x1 : log1pf(expf(x1));
    float sp2 = x2 > 20.f ? x2 : log1pf(expf(x2));
    red[t] = sp1 + sp2;
    __syncthreads();
    for (int off = 128; off; off >>= 1) {
        if (t < off) red[t] += red[t + off];
        __syncthreads();
    }
    if (t < 16) {
        float mv = 1e30f;
        for (int nn = 0; nn < 16; ++nn) mv = fminf(mv, dist_s[t * 16 + nn]);
        minv[t] = mv;
    }
    __syncthreads();
    if (t == 0) {
        float psum = 0.f, msum = 0.f;
        for (int qq = 0; qq < 16; ++qq) { psum += pos_s[qq]; msum += minv[qq]; }
        out[0] = red[0] / 48.f;
        out[1] = psum / 16.f;
        out[2] = msum / 16.f;
    }
}

extern "C" void kernel_launch(void* const* d_in, const int* in_sizes, int n_in,
                              void* d_out, int out_size, void* d_ws, size_t ws_size,
                              hipStream_t stream) {
    const float* sat = (const float*)d_in[0];
    const float* grd = (const float*)d_in[1];
    float* out = (float*)d_out;
    float* ws  = (float*)d_ws;
    const unsigned short* satp = (const unsigned short*)((char*)d_ws + OFF_SATP_B);
    const unsigned short* grdb = (const unsigned short*)((char*)d_ws + OFF_GRDB_B);
    float* part = (float*)((char*)d_ws + OFF_PART_B);

    k_prep  <<<1024,      256, 0, stream>>>(sat, grd, ws);
    k_scale <<<16,        320, 0, stream>>>(ws);
    k_corr  <<<NBLK_CORR, 256, 0, stream>>>(satp, grdb, part);
    k_reduce<<<NSHIFT,    256, 0, stream>>>(part, ws);
    k_final <<<1,         256, 0, stream>>>(ws, out);
}